// Round 4
// baseline (434.851 us; speedup 1.0000x reference)
//
#include <hip/hip_runtime.h>
#include <stdint.h>

#define Bsz 16384
#define ROWS 64
#define N1 1536
#define K1 1024
#define N2 512
#define K2 512

typedef __bf16 bf16x8 __attribute__((ext_vector_type(8)));
typedef float f32x4 __attribute__((ext_vector_type(4)));

__device__ __forceinline__ unsigned short f2bf(float f) {
    union { float f; unsigned int u; } v; v.f = f;
    unsigned int u = v.u;
    return (unsigned short)((u + 0x7fffu + ((u >> 16) & 1u)) >> 16);
}
__device__ __forceinline__ float bf2f(unsigned short s) {
    union { float f; unsigned int u; } v; v.u = ((unsigned int)s) << 16;
    return v.f;
}
__device__ __forceinline__ float sigm(float x) { return 1.0f / (1.0f + __expf(-x)); }

// ============ weight/bias prep (verified in round 3) ============
// W1 [1536][1024] bf16, interleaved cols: n = g*512 + j*2 + part (g:0=r,1=z,2=h1)
//   k<512 multiplies [x_re|h_re]; k>=512 multiplies [x_im|h_im]
//   part0: {wre, -wim}; part1: {wim, wre}
// W2 [512][512] bf16, cols n2 = j*2+part; rows k2<256 -> rh_re, else rh_im.
// bias1[1536] f32 same interleaved order.
__global__ void build_weights(
    const float* __restrict__ wr_re, const float* __restrict__ wr_im,
    const float* __restrict__ wz_re, const float* __restrict__ wz_im,
    const float* __restrict__ wh_re, const float* __restrict__ wh_im,
    const float* __restrict__ ur_re, const float* __restrict__ ur_im,
    const float* __restrict__ uz_re, const float* __restrict__ uz_im,
    const float* __restrict__ uh_re, const float* __restrict__ uh_im,
    const float* __restrict__ br_re, const float* __restrict__ br_im,
    const float* __restrict__ bz_re, const float* __restrict__ bz_im,
    const float* __restrict__ bh_re, const float* __restrict__ bh_im,
    unsigned short* __restrict__ W1, unsigned short* __restrict__ W2,
    float* __restrict__ bias1) {
    int idx = blockIdx.x * blockDim.x + threadIdx.x;
    if (idx < N1 * K1) {
        int n = idx / K1, k = idx % K1;
        int g = n >> 9, q = n & 511, j = q >> 1, part = q & 1;
        bool second = (k >= 512);
        int kk = k & 511;
        const float *Wre, *Wim, *Ure, *Uim;
        if (g == 0)      { Wre = wr_re; Wim = wr_im; Ure = ur_re; Uim = ur_im; }
        else if (g == 1) { Wre = wz_re; Wim = wz_im; Ure = uz_re; Uim = uz_im; }
        else             { Wre = wh_re; Wim = wh_im; Ure = uh_re; Uim = uh_im; }
        float wre, wim;
        if (g < 2) {
            wre = Wre[j * 512 + kk];
            wim = Wim[j * 512 + kk];
            if (kk >= 256) { wre += Ure[j * 256 + kk - 256]; wim += Uim[j * 256 + kk - 256]; }
        } else {
            if (kk < 256) { wre = Wre[j * 512 + kk];       wim = Wim[j * 512 + kk]; }
            else          { wre = Ure[j * 256 + kk - 256]; wim = Uim[j * 256 + kk - 256]; }
        }
        float val = (part == 0) ? (second ? -wim : wre) : (second ? wre : wim);
        W1[idx] = f2bf(val);
        return;
    }
    int i2 = idx - N1 * K1;
    if (i2 < N2 * K2) {
        int n2 = i2 / K2, k2 = i2 % K2;
        int j = n2 >> 1, part = n2 & 1;
        bool second = (k2 >= 256);
        int kk = k2 & 255;
        float wre = wh_re[j * 512 + 256 + kk];
        float wim = wh_im[j * 512 + 256 + kk];
        float val = (part == 0) ? (second ? -wim : wre) : (second ? wre : wim);
        W2[i2] = f2bf(val);
        return;
    }
    int i3 = i2 - N2 * K2;
    if (i3 < N1) {
        int g = i3 >> 9, q = i3 & 511, j = q >> 1, part = q & 1;
        const float* re = (g == 0) ? br_re : ((g == 1) ? bz_re : bh_re);
        const float* im = (g == 0) ? br_im : ((g == 1) ? bz_im : bh_im);
        bias1[i3] = part ? (re[j] + im[j]) : (re[j] - im[j]);
    }
}

// ============ fully fused GRU cell ============
// 1 block = 64 batch rows, 512 threads (8 waves), 1 block/CU, grid = 256.
// sA [64][1024] bf16 (128KB LDS), row = [x_re|h_re|x_im|h_im], 16B slots
// XOR-swizzled: slot' = slot ^ (row&7).  W fragments register-direct from L2.
// Phases: stage -> z -> r(->rh regs) -> h1 -> rh into dead x-slots -> GEMM2 -> epilogue.
__global__ __launch_bounds__(512, 2)
void fused_gru(const float* __restrict__ xr, const float* __restrict__ xi,
               const float* __restrict__ hr, const float* __restrict__ hi,
               const unsigned short* __restrict__ W1,
               const unsigned short* __restrict__ W2,
               const float* __restrict__ bias1,
               float* __restrict__ outp) {
    __shared__ __align__(16) unsigned short sA[ROWS * 1024];   // 131072 B
    const int tid  = threadIdx.x;
    const int lane = tid & 63;
    const int w    = tid >> 6;        // wave 0..7
    const int r0   = blockIdx.x * ROWS;
    const int fr   = lane & 15;       // fragment row / out col
    const int fc   = lane >> 4;       // fragment k-chunk / out row group
    const int ccol = fr;
    const int crow = fc * 4;

    // ---- stage x|h -> sA (f32 -> bf16, swizzled) ----
    {
        const int q    = tid & 255;          // 8B unit within a 2KB row
        const int arr  = q >> 6;             // 0:x_re 1:h_re 2:x_im 3:h_im
        const int col  = (q & 63) * 4;
        const float* src = (arr == 0) ? xr : (arr == 1) ? hr : (arr == 2) ? xi : hi;
        const int rbase = tid >> 8;          // 0 or 1
        const int slot  = q >> 1;
#pragma unroll
        for (int i = 0; i < 32; i++) {
            int rr = rbase + i * 2;
            f32x4 v = *(const f32x4*)(src + (size_t)(r0 + rr) * 256 + col);
            unsigned int lo = ((unsigned int)f2bf(v[1]) << 16) | f2bf(v[0]);
            unsigned int hi2 = ((unsigned int)f2bf(v[3]) << 16) | f2bf(v[2]);
            char* p = (char*)sA + rr * 2048 + ((slot ^ (rr & 7)) * 16) + (q & 1) * 8;
            *(uint2*)p = make_uint2(lo, hi2);
        }
    }
    __syncthreads();

    // h_re/h_im reader (LDS, bf16) — slots 32..63 / 96..127
    auto lds_h = [&](int row, int jj, int im) -> float {
        int slot = (im ? 96 : 32) + (jj >> 3);
        const char* p = (const char*)sA + row * 2048 + ((slot ^ (row & 7)) * 16) + (jj & 7) * 2;
        return bf2f(*(const unsigned short*)p);
    };

    // one gate GEMM: acc[nn][m] += A(64 x 1024) * W1_g(cols w*64+nn*16+fr)^T
    auto run_gate = [&](int g, f32x4 (&acc)[4][4]) {
        const unsigned short* Wb = W1 + (size_t)(g * 512 + w * 64 + fr) * 1024 + fc * 8;
#pragma unroll 2
        for (int ks = 0; ks < 32; ks++) {
            bf16x8 af[4];
#pragma unroll
            for (int m = 0; m < 4; m++) {
                int row = m * 16 + fr;
                int slot = (ks * 4 + fc) ^ (row & 7);
                af[m] = *(const bf16x8*)((const char*)sA + row * 2048 + slot * 16);
            }
            bf16x8 bv[4];
#pragma unroll
            for (int nn = 0; nn < 4; nn++)
                bv[nn] = *(const bf16x8*)(Wb + (size_t)nn * 16 * 1024 + ks * 32);
#pragma unroll
            for (int nn = 0; nn < 4; nn++)
#pragma unroll
                for (int m = 0; m < 4; m++)
                    acc[nn][m] = __builtin_amdgcn_mfma_f32_16x16x32_bf16(af[m], bv[nn], acc[nn][m], 0, 0, 0);
        }
    };

    // ---- z gate: compute, add bias, pack preact to bf16 (32 VGPR) ----
    unsigned int zp[4][4][2];
    {
        f32x4 zacc[4][4];
#pragma unroll
        for (int a = 0; a < 4; a++)
#pragma unroll
            for (int b = 0; b < 4; b++) zacc[a][b] = {0.f, 0.f, 0.f, 0.f};
        run_gate(1, zacc);
#pragma unroll
        for (int nn = 0; nn < 4; nn++) {
            float bz = bias1[512 + w * 64 + nn * 16 + ccol];
#pragma unroll
            for (int m = 0; m < 4; m++) {
                unsigned short t0 = f2bf(zacc[nn][m][0] + bz);
                unsigned short t1 = f2bf(zacc[nn][m][1] + bz);
                unsigned short t2 = f2bf(zacc[nn][m][2] + bz);
                unsigned short t3 = f2bf(zacc[nn][m][3] + bz);
                zp[nn][m][0] = ((unsigned int)t1 << 16) | t0;
                zp[nn][m][1] = ((unsigned int)t3 << 16) | t2;
            }
        }
    }

    // ---- r gate -> rh (bf16 packed, 32 VGPR) ----
    unsigned int rhp[4][4][2];
    {
        f32x4 racc[4][4];
#pragma unroll
        for (int a = 0; a < 4; a++)
#pragma unroll
            for (int b = 0; b < 4; b++) racc[a][b] = {0.f, 0.f, 0.f, 0.f};
        run_gate(0, racc);
#pragma unroll
        for (int nn = 0; nn < 4; nn++) {
            int qc = w * 64 + nn * 16 + ccol;
            float br = bias1[qc];
            int jj = qc >> 1;
            int part = qc & 1;
#pragma unroll
            for (int m = 0; m < 4; m++) {
                unsigned short hv[4];
#pragma unroll
                for (int j = 0; j < 4; j++) {
                    int row = m * 16 + crow + j;
                    float s  = sigm(racc[nn][m][j] + br);
                    float sp = __shfl_xor(s, 1);
                    float hre = lds_h(row, jj, 0);
                    float him = lds_h(row, jj, 1);
                    // even lane: rr=s, ri=sp -> rh_re = s*hr - sp*hi
                    // odd  lane: ri=s, rr=sp -> rh_im = s*hr + sp*hi
                    float val = part ? (s * hre + sp * him) : (s * hre - sp * him);
                    hv[j] = f2bf(val);
                }
                rhp[nn][m][0] = ((unsigned int)hv[1] << 16) | hv[0];
                rhp[nn][m][1] = ((unsigned int)hv[3] << 16) | hv[2];
            }
        }
    }

    // ---- h1 gate (acc persists through GEMM2) ----
    f32x4 hacc[4][4];
#pragma unroll
    for (int a = 0; a < 4; a++)
#pragma unroll
        for (int b = 0; b < 4; b++) hacc[a][b] = {0.f, 0.f, 0.f, 0.f};
    run_gate(2, hacc);

    // ---- write rh over dead x-slots (x_re: slots 0..31, x_im: 64..95) ----
    __syncthreads();   // all waves done reading x-slots
#pragma unroll
    for (int nn = 0; nn < 4; nn++) {
        int qc = w * 64 + nn * 16 + ccol;
        int jj = qc >> 1;
        int part = qc & 1;
        int sbase = (jj >> 3) + (part ? 64 : 0);
        int boff = (jj & 7) * 2;
#pragma unroll
        for (int m = 0; m < 4; m++)
#pragma unroll
            for (int j = 0; j < 4; j++) {
                int row = m * 16 + crow + j;
                unsigned short bits = (unsigned short)(rhp[nn][m][j >> 1] >> ((j & 1) * 16));
                char* p = (char*)sA + row * 2048 + (((sbase) ^ (row & 7)) * 16) + boff;
                *(unsigned short*)p = bits;
            }
    }
    __syncthreads();

    // ---- GEMM2: hacc += rh(64 x 512) * W2^T ----
    {
#pragma unroll 2
        for (int ks = 0; ks < 16; ks++) {
            int sb = ks * 4 + ((ks >= 8) ? 32 : 0);   // rh_re slots 0..31, rh_im 64..95
            bf16x8 af[4];
#pragma unroll
            for (int m = 0; m < 4; m++) {
                int row = m * 16 + fr;
                int slot = (sb + fc) ^ (row & 7);
                af[m] = *(const bf16x8*)((const char*)sA + row * 2048 + slot * 16);
            }
            bf16x8 bv[4];
#pragma unroll
            for (int nn = 0; nn < 4; nn++)
                bv[nn] = *(const bf16x8*)(W2 + (size_t)(w * 64 + nn * 16 + fr) * 512 + ks * 32 + fc * 8);
#pragma unroll
            for (int nn = 0; nn < 4; nn++)
#pragma unroll
                for (int m = 0; m < 4; m++)
                    hacc[nn][m] = __builtin_amdgcn_mfma_f32_16x16x32_bf16(af[m], bv[nn], hacc[nn][m], 0, 0, 0);
        }
    }

    // ---- epilogue: z = sigm, hh = tanh, complex h_new, write out ----
#pragma unroll
    for (int nn = 0; nn < 4; nn++) {
        int qc = w * 64 + nn * 16 + ccol;
        float bh = bias1[1024 + qc];
        int jj = qc >> 1;
        int part = qc & 1;
#pragma unroll
        for (int m = 0; m < 4; m++) {
#pragma unroll
            for (int j = 0; j < 4; j++) {
                int row = m * 16 + crow + j;
                float zpre = bf2f((unsigned short)(zp[nn][m][j >> 1] >> ((j & 1) * 16)));
                float z  = sigm(zpre);
                float hh = tanhf(hacc[nn][m][j] + bh);
                float zq = __shfl_xor(z, 1);
                float hq = __shfl_xor(hh, 1);
                float hre = lds_h(row, jj, 0);
                float him = lds_h(row, jj, 1);
                float res = (part == 0)
                    ? (1.f - z) * hre + zq * him + z * hh - zq * hq
                    : (1.f - zq) * him - z * hre + zq * hh + z * hq;
                outp[(size_t)part * ((size_t)Bsz * 256) + (size_t)(r0 + row) * 256 + jj] = res;
            }
        }
    }
}

extern "C" void kernel_launch(void* const* d_in, const int* in_sizes, int n_in,
                              void* d_out, int out_size, void* d_ws, size_t ws_size,
                              hipStream_t stream) {
    const float* x_re = (const float*)d_in[0];
    const float* x_im = (const float*)d_in[1];
    const float* h_re = (const float*)d_in[2];
    const float* h_im = (const float*)d_in[3];
    const float* wr_w_re = (const float*)d_in[4];
    const float* wr_w_im = (const float*)d_in[5];
    const float* wr_b_re = (const float*)d_in[6];
    const float* wr_b_im = (const float*)d_in[7];
    const float* wz_w_re = (const float*)d_in[8];
    const float* wz_w_im = (const float*)d_in[9];
    const float* wz_b_re = (const float*)d_in[10];
    const float* wz_b_im = (const float*)d_in[11];
    const float* wh_w_re = (const float*)d_in[12];
    const float* wh_w_im = (const float*)d_in[13];
    const float* wh_b_re = (const float*)d_in[14];
    const float* wh_b_im = (const float*)d_in[15];
    const float* ur_w_re = (const float*)d_in[16];
    const float* ur_w_im = (const float*)d_in[17];
    const float* uz_w_re = (const float*)d_in[18];
    const float* uz_w_im = (const float*)d_in[19];
    const float* uh_w_re = (const float*)d_in[20];
    const float* uh_w_im = (const float*)d_in[21];

    // ws: W1 3,145,728 | W2 524,288 | bias1 6,144  (total 3,676,160 B)
    char* ws = (char*)d_ws;
    unsigned short* W1    = (unsigned short*)(ws);
    unsigned short* W2    = (unsigned short*)(ws + 3145728);
    float*          bias1 = (float*)         (ws + 3670016);

    const int prep_elems = N1 * K1 + N2 * K2 + N1;
    build_weights<<<(prep_elems + 255) / 256, 256, 0, stream>>>(
        wr_w_re, wr_w_im, wz_w_re, wz_w_im, wh_w_re, wh_w_im,
        ur_w_re, ur_w_im, uz_w_re, uz_w_im, uh_w_re, uh_w_im,
        wr_b_re, wr_b_im, wz_b_re, wz_b_im, wh_b_re, wh_b_im,
        W1, W2, bias1);

    fused_gru<<<Bsz / ROWS, 512, 0, stream>>>(
        x_re, x_im, h_re, h_im, W1, W2, bias1, (float*)d_out);
}

// Round 5
// 314.682 us; speedup vs baseline: 1.3819x; 1.3819x over previous
//
#include <hip/hip_runtime.h>
#include <stdint.h>

#define Bsz 16384
#define K1 1024
#define N1 1536
#define K2 512
#define N2 512

typedef __bf16 bf16x8 __attribute__((ext_vector_type(8)));
typedef float f32x4 __attribute__((ext_vector_type(4)));

__device__ __forceinline__ unsigned short f2bf(float f) {
    union { float f; unsigned int u; } v; v.f = f;
    unsigned int u = v.u;
    return (unsigned short)((u + 0x7fffu + ((u >> 16) & 1u)) >> 16);
}
__device__ __forceinline__ float sigm(float x) { return 1.0f / (1.0f + __expf(-x)); }

// ============ weight/bias prep (verified rounds 3/4) ============
// W1 [1536][1024] bf16, interleaved cols: n = g*512 + j*2 + part (g:0=r,1=z,2=h1)
//   k<512 multiplies [x_re|h_re]; k>=512 multiplies [x_im|h_im]
//   part0: {wre, -wim}; part1: {wim, wre}
// W2 [512][512] bf16, cols n2 = j*2+part; rows k2<256 -> rh_re, else rh_im.
// bias1[1536] f32, same interleaved order.
__global__ void build_weights(
    const float* __restrict__ wr_re, const float* __restrict__ wr_im,
    const float* __restrict__ wz_re, const float* __restrict__ wz_im,
    const float* __restrict__ wh_re, const float* __restrict__ wh_im,
    const float* __restrict__ ur_re, const float* __restrict__ ur_im,
    const float* __restrict__ uz_re, const float* __restrict__ uz_im,
    const float* __restrict__ uh_re, const float* __restrict__ uh_im,
    const float* __restrict__ br_re, const float* __restrict__ br_im,
    const float* __restrict__ bz_re, const float* __restrict__ bz_im,
    const float* __restrict__ bh_re, const float* __restrict__ bh_im,
    unsigned short* __restrict__ W1, unsigned short* __restrict__ W2,
    float* __restrict__ bias1) {
    int idx = blockIdx.x * blockDim.x + threadIdx.x;
    if (idx < N1 * K1) {
        int n = idx / K1, k = idx % K1;
        int g = n >> 9, q = n & 511, j = q >> 1, part = q & 1;
        bool second = (k >= 512);
        int kk = k & 511;
        const float *Wre, *Wim, *Ure, *Uim;
        if (g == 0)      { Wre = wr_re; Wim = wr_im; Ure = ur_re; Uim = ur_im; }
        else if (g == 1) { Wre = wz_re; Wim = wz_im; Ure = uz_re; Uim = uz_im; }
        else             { Wre = wh_re; Wim = wh_im; Ure = uh_re; Uim = uh_im; }
        float wre, wim;
        if (g < 2) {
            wre = Wre[j * 512 + kk];
            wim = Wim[j * 512 + kk];
            if (kk >= 256) { wre += Ure[j * 256 + kk - 256]; wim += Uim[j * 256 + kk - 256]; }
        } else {
            if (kk < 256) { wre = Wre[j * 512 + kk];       wim = Wim[j * 512 + kk]; }
            else          { wre = Ure[j * 256 + kk - 256]; wim = Uim[j * 256 + kk - 256]; }
        }
        float val = (part == 0) ? (second ? -wim : wre) : (second ? wre : wim);
        W1[idx] = f2bf(val);
        return;
    }
    int i2 = idx - N1 * K1;
    if (i2 < N2 * K2) {
        int n2 = i2 / K2, k2 = i2 % K2;
        int j = n2 >> 1, part = n2 & 1;
        bool second = (k2 >= 256);
        int kk = k2 & 255;
        float wre = wh_re[j * 512 + 256 + kk];
        float wim = wh_im[j * 512 + 256 + kk];
        float val = (part == 0) ? (second ? -wim : wre) : (second ? wre : wim);
        W2[i2] = f2bf(val);
        return;
    }
    int i3 = i2 - N2 * K2;
    if (i3 < N1) {
        int g = i3 >> 9, q = i3 & 511, j = q >> 1, part = q & 1;
        const float* re = (g == 0) ? br_re : ((g == 1) ? bz_re : bh_re);
        const float* im = (g == 0) ? br_im : ((g == 1) ? bz_im : bh_im);
        bias1[i3] = part ? (re[j] + im[j]) : (re[j] - im[j]);
    }
}

// ============ A builder: A = [x_re|h_re|x_im|h_im] bf16 [B, 1024] ============
__global__ void build_a(const float* __restrict__ xr, const float* __restrict__ hr,
                        const float* __restrict__ xi, const float* __restrict__ hi,
                        unsigned short* __restrict__ a) {
    int idx = blockIdx.x * blockDim.x + threadIdx.x;
    if (idx >= Bsz * K1 / 4) return;
    int t = idx * 4;
    int b = t >> 10;
    int k = t & 1023;
    const float* src;
    int off;
    if (k < 256)      { src = xr; off = b * 256 + k; }
    else if (k < 512) { src = hr; off = b * 256 + k - 256; }
    else if (k < 768) { src = xi; off = b * 256 + k - 512; }
    else              { src = hi; off = b * 256 + k - 768; }
    f32x4 v = *(const f32x4*)(src + off);
    ushort4 o;
    o.x = f2bf(v[0]); o.y = f2bf(v[1]); o.z = f2bf(v[2]); o.w = f2bf(v[3]);
    *(ushort4*)(a + t) = o;
}

// ============ GEMM core: C = A[M,K] * Bm[N,K]^T, fused epilogues ============
// 128x128 tile, BK=32, 256 thr (4 waves 2x2), mfma_f32_16x16x32_bf16, 16KB LDS.
// LDS paired-line layout: line L (128B, 8 x 16B slots) holds tile rows 2L,2L+1.
//   slot' = (p*4 + c) ^ (L&7)   (p=row parity, c=k-chunk 0..3)
// Line base = L*128B ≡ bank 0, so slot permutation spreads each 16-lane read
// phase across all 32 banks at 2 lanes/bank (wave64 minimum) -> 0 conflicts.
// Write side: linear LDS dest (global_load_lds), pre-swizzled GLOBAL chunk.
// MODE 1: epilogue g==0: rh->A2 bf16; g==1: z preact->C1z; g==2: h1 preact->C1h
// MODE 2: epilogue z/tanh/h_new -> out.  (both verified round 3)
template<int K, int NBX, int MODE>
__global__ __launch_bounds__(256)
void gemm_fused(const unsigned short* __restrict__ A,
                const unsigned short* __restrict__ Bm,
                const float* __restrict__ bias,
                const float* __restrict__ hre_g,
                const float* __restrict__ him_g,
                float* __restrict__ c1z,
                float* __restrict__ c1h,
                unsigned short* __restrict__ A2,
                float* __restrict__ outp) {
    __shared__ __align__(16) unsigned short sA[128 * 32];   // 8KB, 64 lines
    __shared__ __align__(16) unsigned short sB[128 * 32];
    const int tid  = threadIdx.x;
    const int lane = tid & 63;
    const int wid  = tid >> 6;

    // XCD-aware bijective swizzle (gridDim.x % 8 == 0 for all launches)
    const int nwg = gridDim.x;
    const int cpx = nwg >> 3;
    const int wgid = (blockIdx.x & 7) * cpx + (blockIdx.x >> 3);
    const int bx = wgid % NBX;
    const int by = wgid / NBX;
    const int rowA0 = by * 128;
    const int col0  = bx * 128;
    const int wm = (wid >> 1) * 64;
    const int wn = (wid & 1) * 64;

    f32x4 acc[4][4];
#pragma unroll
    for (int i = 0; i < 4; i++)
#pragma unroll
        for (int j = 0; j < 4; j++) acc[i][j] = {0.f, 0.f, 0.f, 0.f};

    // staging decomposition: lane -> (local line, slot)
    const int ll   = lane >> 3;          // 0..7 local line within an issue
    const int sl   = lane & 7;           // LDS slot within line
    // fragment indices
    const int fr = lane & 15;
    const int fc = lane >> 4;            // k-chunk 0..3

    for (int k0 = 0; k0 < K; k0 += 32) {
        __syncthreads();
#pragma unroll
        for (int i = 0; i < 2; i++) {
            int Lb = wid * 16 + i * 8;               // base line of this issue
            int L  = Lb + ll;
            int sidx = sl ^ (L & 7);                 // global (p,c) packed
            int grow = 2 * L + (sidx >> 2);          // tile row
            const unsigned short* gp = A + (size_t)(rowA0 + grow) * K + k0 + (sidx & 3) * 8;
            unsigned short* lp = sA + Lb * 64 + lane * 8;   // linear dest
            __builtin_amdgcn_global_load_lds((const __attribute__((address_space(1))) void*)gp,
                                             (__attribute__((address_space(3))) void*)lp,
                                             16, 0, 0);
        }
#pragma unroll
        for (int i = 0; i < 2; i++) {
            int Lb = wid * 16 + i * 8;
            int L  = Lb + ll;
            int sidx = sl ^ (L & 7);
            int grow = 2 * L + (sidx >> 2);
            const unsigned short* gp = Bm + (size_t)(col0 + grow) * K + k0 + (sidx & 3) * 8;
            unsigned short* lp = sB + Lb * 64 + lane * 8;
            __builtin_amdgcn_global_load_lds((const __attribute__((address_space(1))) void*)gp,
                                             (__attribute__((address_space(3))) void*)lp,
                                             16, 0, 0);
        }
        __syncthreads();

        bf16x8 af[4], bfr[4];
#pragma unroll
        for (int m = 0; m < 4; m++) {
            int r = wm + m * 16 + fr;
            int L = r >> 1;
            int slot = ((r & 1) * 4 + fc) ^ (L & 7);
            af[m] = *(const bf16x8*)(sA + L * 64 + slot * 8);
        }
#pragma unroll
        for (int n = 0; n < 4; n++) {
            int r = wn + n * 16 + fr;
            int L = r >> 1;
            int slot = ((r & 1) * 4 + fc) ^ (L & 7);
            bfr[n] = *(const bf16x8*)(sB + L * 64 + slot * 8);
        }
#pragma unroll
        for (int m = 0; m < 4; m++)
#pragma unroll
            for (int n = 0; n < 4; n++)
                acc[m][n] = __builtin_amdgcn_mfma_f32_16x16x32_bf16(af[m], bfr[n], acc[m][n], 0, 0, 0);
    }

    // epilogue: C/D layout col=lane&15, row=(lane>>4)*4+reg  [m89/m91]
    const int crow = (lane >> 4) * 4;
    const int ccol = lane & 15;

    if constexpr (MODE == 1) {
        const int g = col0 >> 9;   // 0=r, 1=z, 2=h1 (uniform per block)
#pragma unroll
        for (int m = 0; m < 4; m++) {
#pragma unroll
            for (int n = 0; n < 4; n++) {
                int nc = col0 + wn + n * 16 + ccol;    // global col
                int qc = nc & 511;                      // within-gate col
                int jj = qc >> 1;
                int part = qc & 1;
                float bv = bias[nc];
#pragma unroll
                for (int j = 0; j < 4; j++) {
                    int gr = rowA0 + wm + m * 16 + crow + j;
                    float v = acc[m][n][j] + bv;
                    if (g == 0) {
                        float s  = sigm(v);
                        float sp = __shfl_xor(s, 1);
                        float hr = hre_g[gr * 256 + jj];
                        float hi = him_g[gr * 256 + jj];
                        // even(part0): rr=s, ri=sp -> rh_re = s*hr - sp*hi
                        // odd (part1): ri=s, rr=sp -> rh_im = s*hr + sp*hi
                        float val = part ? (s * hr + sp * hi) : (s * hr - sp * hi);
                        A2[(size_t)gr * 512 + part * 256 + jj] = f2bf(val);
                    } else if (g == 1) {
                        c1z[(size_t)gr * 512 + qc] = v;
                    } else {
                        c1h[(size_t)gr * 512 + qc] = v;
                    }
                }
            }
        }
    } else {
#pragma unroll
        for (int m = 0; m < 4; m++) {
#pragma unroll
            for (int n = 0; n < 4; n++) {
                int qc = col0 + wn + n * 16 + ccol;     // 0..511 interleaved
                int jj = qc >> 1;
                int part = qc & 1;
#pragma unroll
                for (int j = 0; j < 4; j++) {
                    int gr = rowA0 + wm + m * 16 + crow + j;
                    float zpre = c1z[(size_t)gr * 512 + qc];
                    float hpre = c1h[(size_t)gr * 512 + qc] + acc[m][n][j];
                    float z  = sigm(zpre);
                    float hh = tanhf(hpre);
                    float zp  = __shfl_xor(z, 1);
                    float hhp = __shfl_xor(hh, 1);
                    float hr = hre_g[gr * 256 + jj];
                    float hi = him_g[gr * 256 + jj];
                    float res;
                    if (part == 0)
                        res = (1.f - z) * hr + zp * hi + z * hh - zp * hhp;
                    else
                        res = (1.f - zp) * hi - z * hr + zp * hh + z * hhp;
                    outp[(size_t)part * (Bsz * 256) + (size_t)gr * 256 + jj] = res;
                }
            }
        }
    }
}

extern "C" void kernel_launch(void* const* d_in, const int* in_sizes, int n_in,
                              void* d_out, int out_size, void* d_ws, size_t ws_size,
                              hipStream_t stream) {
    const float* x_re = (const float*)d_in[0];
    const float* x_im = (const float*)d_in[1];
    const float* h_re = (const float*)d_in[2];
    const float* h_im = (const float*)d_in[3];
    const float* wr_w_re = (const float*)d_in[4];
    const float* wr_w_im = (const float*)d_in[5];
    const float* wr_b_re = (const float*)d_in[6];
    const float* wr_b_im = (const float*)d_in[7];
    const float* wz_w_re = (const float*)d_in[8];
    const float* wz_w_im = (const float*)d_in[9];
    const float* wz_b_re = (const float*)d_in[10];
    const float* wz_b_im = (const float*)d_in[11];
    const float* wh_w_re = (const float*)d_in[12];
    const float* wh_w_im = (const float*)d_in[13];
    const float* wh_b_re = (const float*)d_in[14];
    const float* wh_b_im = (const float*)d_in[15];
    const float* ur_w_re = (const float*)d_in[16];
    const float* ur_w_im = (const float*)d_in[17];
    const float* uz_w_re = (const float*)d_in[18];
    const float* uz_w_im = (const float*)d_in[19];
    const float* uh_w_re = (const float*)d_in[20];
    const float* uh_w_im = (const float*)d_in[21];

    // ws layout (no aliasing). Total 121,116,672 B.
    char* ws = (char*)d_ws;
    unsigned short* W1    = (unsigned short*)(ws);               //  3,145,728 B
    unsigned short* W2    = (unsigned short*)(ws + 3145728);     //    524,288 B
    float*          bias1 = (float*)         (ws + 3670016);     //      6,144 B
    unsigned short* A_bf  = (unsigned short*)(ws + 3676160);     // 33,554,432 B
    unsigned short* A2    = (unsigned short*)(ws + 37230592);    // 16,777,216 B
    float*          C1z   = (float*)         (ws + 54007808);    // 33,554,432 B
    float*          C1h   = (float*)         (ws + 87562240);    // 33,554,432 B

    const int prep_elems = N1 * K1 + N2 * K2 + N1;
    build_weights<<<(prep_elems + 255) / 256, 256, 0, stream>>>(
        wr_w_re, wr_w_im, wz_w_re, wz_w_im, wh_w_re, wh_w_im,
        ur_w_re, ur_w_im, uz_w_re, uz_w_im, uh_w_re, uh_w_im,
        wr_b_re, wr_b_im, wz_b_re, wz_b_im, wh_b_re, wh_b_im,
        W1, W2, bias1);

    build_a<<<(Bsz * K1 / 4 + 255) / 256, 256, 0, stream>>>(x_re, h_re, x_im, h_im, A_bf);

    gemm_fused<K1, N1 / 128, 1><<<(N1 / 128) * (Bsz / 128), 256, 0, stream>>>(
        A_bf, W1, bias1, h_re, h_im, C1z, C1h, A2, nullptr);

    gemm_fused<K2, N2 / 128, 2><<<(N2 / 128) * (Bsz / 128), 256, 0, stream>>>(
        A2, W2, nullptr, h_re, h_im, C1z, C1h, nullptr, (float*)d_out);
}